// Round 2
// baseline (607.407 us; speedup 1.0000x reference)
//
#include <hip/hip_runtime.h>

#define B_ 8
#define C_ 128
#define WH_ 2304
#define N_ 8192

typedef unsigned short u16;
typedef float f32x4 __attribute__((ext_vector_type(4)));
typedef short s16x8 __attribute__((ext_vector_type(8)));

typedef const unsigned int __attribute__((address_space(1))) ga_u32;
typedef unsigned int __attribute__((address_space(3))) lds_u32;

__device__ __forceinline__ float bf2f(u16 u){
    union { unsigned int i; float f; } x; x.i = ((unsigned int)u) << 16; return x.f;
}
__device__ __forceinline__ u16 f2bf(float f){
    union { float f; unsigned int i; } x; x.f = f;
    unsigned int r = x.i + 0x7fffu + ((x.i >> 16) & 1u);
    return (u16)(r >> 16);
}
// element index inside a [rows][128] bf16 LDS tile with 16B-block xor swizzle
__device__ __forceinline__ int swz(int row, int col){
    return row*128 + ((((col >> 3) ^ (row & 15)) << 3) | (col & 7));
}
__device__ __forceinline__ f32x4 fzero(){ f32x4 z = {0.f, 0.f, 0.f, 0.f}; return z; }
__device__ __forceinline__ f32x4 mfma16(s16x8 a, s16x8 b, f32x4 c){
    return __builtin_amdgcn_mfma_f32_16x16x32_bf16(a, b, c, 0, 0, 0);
}
__device__ __forceinline__ void gld16(const void* g, void* l){
    __builtin_amdgcn_global_load_lds((ga_u32*)g, (lds_u32*)l, 16, 0, 0);
}
__device__ __forceinline__ s16x8 ldsf(const u16* p){ return *(const s16x8*)p; }

// ---------------- K1: pq = f0^T@Wq+bq (+gate fuse), geo = ge@Wg+bg ----------------
__global__ __launch_bounds__(256) void k_proj_qg(
    const float* __restrict__ feat0, const float* __restrict__ geo,
    const float* __restrict__ Wq, const float* __restrict__ bq,
    const float* __restrict__ Wg, const float* __restrict__ bg,
    const float* __restrict__ Wgate, const float* __restrict__ bgate,
    u16* __restrict__ Qb, u16* __restrict__ Gb)
{
    __shared__ __attribute__((aligned(16))) u16 Aq[64*128];
    __shared__ __attribute__((aligned(16))) u16 Ag[64*128];
    __shared__ __attribute__((aligned(16))) u16 WqT[128*128];
    __shared__ __attribute__((aligned(16))) u16 WgT[128*128];
    const int t = threadIdx.x;
    const int b = blockIdx.x / 36;
    const int r0 = (blockIdx.x % 36) * 64;
    {
        const int wl = t & 63;
        for (int c = t >> 6; c < 128; c += 4)
            Aq[swz(wl, c)] = f2bf(feat0[(size_t)(b*C_ + c)*WH_ + r0 + wl]);
    }
    for (int idx = t; idx < 64*128; idx += 256){
        int r = idx >> 7, c = idx & 127;
        Ag[swz(r, c)] = f2bf(geo[(size_t)(b*WH_ + r0 + r)*C_ + c]);
    }
    for (int idx = t; idx < 128*128; idx += 256){
        int k = idx >> 7, n = idx & 127;
        WqT[swz(n, k)] = f2bf(Wq[idx]);
        WgT[swz(n, k)] = f2bf(Wg[idx]);
    }
    __syncthreads();
    const int lane = t & 63, w = t >> 6;
    const int q = lane >> 4, m = lane & 15;
    const int rw = w * 16;
    f32x4 accq[8], accg[8];
    #pragma unroll
    for (int ct = 0; ct < 8; ct++){ accq[ct] = fzero(); accg[ct] = fzero(); }
    #pragma unroll
    for (int kt = 0; kt < 4; kt++){
        const int ar = rw + m;
        s16x8 aq = ldsf(&Aq[ar*128 + (((kt*4 + q) ^ (ar & 15)) << 3)]);
        s16x8 ag = ldsf(&Ag[ar*128 + (((kt*4 + q) ^ (ar & 15)) << 3)]);
        #pragma unroll
        for (int ct = 0; ct < 8; ct++){
            const int bn = ct*16 + m;
            s16x8 b1 = ldsf(&WqT[bn*128 + (((kt*4 + q) ^ (bn & 15)) << 3)]);
            s16x8 b2 = ldsf(&WgT[bn*128 + (((kt*4 + q) ^ (bn & 15)) << 3)]);
            accq[ct] = mfma16(aq, b1, accq[ct]);
            accg[ct] = mfma16(ag, b2, accg[ct]);
        }
    }
    float bqv[8], bgv[8], w1v[8], w2v[8];
    #pragma unroll
    for (int ct = 0; ct < 8; ct++){
        int col = ct*16 + m;
        bqv[ct] = bq[col]; bgv[ct] = bg[col];
        w1v[ct] = Wgate[col]; w2v[ct] = Wgate[C_ + col];
    }
    const float bg0 = bgate[0];
    float gs[4];
    #pragma unroll
    for (int i = 0; i < 4; i++){
        float p = 0.f;
        #pragma unroll
        for (int ct = 0; ct < 8; ct++)
            p += (accq[ct][i] + bqv[ct]) * w1v[ct] + (accg[ct][i] + bgv[ct]) * w2v[ct];
        gs[i] = p;
    }
    #pragma unroll
    for (int off = 1; off < 16; off <<= 1){
        #pragma unroll
        for (int i = 0; i < 4; i++)
            gs[i] += __shfl_xor(gs[i], off, 64);
    }
    #pragma unroll
    for (int i = 0; i < 4; i++){
        const float gate = 1.f / (1.f + __expf(-(gs[i] + bg0)));
        const int row = r0 + rw + q*4 + i;
        #pragma unroll
        for (int ct = 0; ct < 8; ct++){
            const int col = ct*16 + m;
            const float ge = accg[ct][i] + bgv[ct];
            const float pq = accq[ct][i] + bqv[ct] + gate * ge;
            Qb[(size_t)(b*WH_ + row)*C_ + col] = f2bf(pq);
            Gb[(size_t)(b*WH_ + row)*C_ + col] = f2bf(ge);
        }
    }
}

// ---------------- K2: pk/pv projections; Vb stored transposed [B][C][N] ----------------
__global__ __launch_bounds__(256) void k_proj_kv(
    const float* __restrict__ feat1,
    const float* __restrict__ Wk, const float* __restrict__ bk,
    const float* __restrict__ Wv, const float* __restrict__ bv,
    u16* __restrict__ Kb, u16* __restrict__ Vb)
{
    __shared__ __attribute__((aligned(16))) u16 Af[64*128];
    __shared__ __attribute__((aligned(16))) u16 WkT[128*128];
    __shared__ __attribute__((aligned(16))) u16 WvT[128*128];
    const int t = threadIdx.x;
    const int b = blockIdx.x >> 7;
    const int n0 = (blockIdx.x & 127) * 64;
    {
        const int nl = t & 63;
        for (int c = t >> 6; c < 128; c += 4)
            Af[swz(nl, c)] = f2bf(feat1[(size_t)(b*C_ + c)*N_ + n0 + nl]);
    }
    for (int idx = t; idx < 128*128; idx += 256){
        int k = idx >> 7, n = idx & 127;
        WkT[swz(n, k)] = f2bf(Wk[idx]);
        WvT[swz(n, k)] = f2bf(Wv[idx]);
    }
    __syncthreads();
    const int lane = t & 63, w = t >> 6;
    const int q = lane >> 4, m = lane & 15;
    const int rw = w * 16;
    f32x4 ak[8], av[8];
    #pragma unroll
    for (int ct = 0; ct < 8; ct++){ ak[ct] = fzero(); av[ct] = fzero(); }
    #pragma unroll
    for (int kt = 0; kt < 4; kt++){
        const int ar = rw + m;
        s16x8 a = ldsf(&Af[ar*128 + (((kt*4 + q) ^ (ar & 15)) << 3)]);
        #pragma unroll
        for (int ct = 0; ct < 8; ct++){
            const int bn = ct*16 + m;
            ak[ct] = mfma16(a, ldsf(&WkT[bn*128 + (((kt*4 + q) ^ (bn & 15)) << 3)]), ak[ct]);
            av[ct] = mfma16(a, ldsf(&WvT[bn*128 + (((kt*4 + q) ^ (bn & 15)) << 3)]), av[ct]);
        }
    }
    #pragma unroll
    for (int ct = 0; ct < 8; ct++){
        const int col = ct*16 + m;
        const float bkv = bk[col];
        #pragma unroll
        for (int i = 0; i < 4; i++){
            const int row = n0 + rw + q*4 + i;
            Kb[(size_t)(b*N_ + row)*C_ + col] = f2bf(ak[ct][i] + bkv);
        }
    }
    __syncthreads();               // all waves done reading WvT
    u16* Tv = WvT;                 // reuse as [128][68] transpose staging
    #pragma unroll
    for (int ct = 0; ct < 8; ct++){
        const int col = ct*16 + m;
        const float bvv = bv[col];
        #pragma unroll
        for (int i = 0; i < 4; i++){
            const int nl = rw + q*4 + i;
            Tv[col*68 + nl] = f2bf(av[ct][i] + bvv);
        }
    }
    __syncthreads();
    for (int idx = t; idx < 128*64; idx += 256){
        int c = idx >> 6, nl = idx & 63;
        Vb[(size_t)(b*C_ + c)*N_ + n0 + nl] = Tv[c*68 + nl];
    }
}

// ---------------- K3: flash attention, 512 blocks x 18 chunk-units ----------------
__global__ __launch_bounds__(256, 2) void k_flash(
    const u16* __restrict__ Qb, const u16* __restrict__ Kb, const u16* __restrict__ Vb,
    u16* __restrict__ Opart, float* __restrict__ Mp, float* __restrict__ Lp)
{
    __shared__ __attribute__((aligned(16))) u16 KP[128*128];   // K tile, then P tile
    __shared__ __attribute__((aligned(16))) u16 Vt[128*128];   // V^T tile [c][n]
    const int t = threadIdx.x;
    const int lane = t & 63, w = t >> 6;
    const int q = lane >> 4, m = lane & 15;
    const int rw = w * 32;
    const int g = blockIdx.x;
    int u = g * 18;
    const int uend = u + 18;
    while (u < uend){
        const int bqt = u >> 6;
        const int ci0 = u & 63;
        int ciN = uend - u; { int rem = 64 - ci0; if (ciN > rem) ciN = rem; }
        const int b = bqt / 18;
        const int r0 = (bqt % 18) * 128;
        s16x8 qf[2][4];
        #pragma unroll
        for (int rt = 0; rt < 2; rt++){
            #pragma unroll
            for (int kt = 0; kt < 4; kt++)
                qf[rt][kt] = *(const s16x8*)&Qb[(size_t)(b*WH_ + r0 + rw + rt*16 + m)*C_ + kt*32 + q*8];
        }
        f32x4 o[2][8];
        #pragma unroll
        for (int rt = 0; rt < 2; rt++){
            #pragma unroll
            for (int ct = 0; ct < 8; ct++) o[rt][ct] = fzero();
        }
        float mrow[2][4], lrow[2][4];
        #pragma unroll
        for (int rt = 0; rt < 2; rt++){
            #pragma unroll
            for (int i = 0; i < 4; i++){ mrow[rt][i] = -3.0e38f; lrow[rt][i] = 0.f; }
        }
        for (int ci = ci0; ci < ci0 + ciN; ci++){
            const int n0 = ci * 128;
            __syncthreads();   // prev PV reads of KP/Vt complete
            #pragma unroll
            for (int uu = 0; uu < 8; uu++){
                const int un = w + uu*4;
                const int nr = un*4 + q;   // K row / V channel (per-lane)
                gld16(Kb + (size_t)(b*N_ + n0 + nr)*C_ + ((m ^ (nr & 15)) << 3), &KP[un*512]);
                gld16(Vb + (size_t)(b*C_ + nr)*N_ + n0 + ((m ^ (nr & 15)) << 3), &Vt[un*512]);
            }
            __syncthreads();   // drains vmcnt: K,V visible
            f32x4 s[2][8];
            #pragma unroll
            for (int rt = 0; rt < 2; rt++){
                #pragma unroll
                for (int ct = 0; ct < 8; ct++) s[rt][ct] = fzero();
            }
            #pragma unroll
            for (int kt = 0; kt < 4; kt++){
                #pragma unroll
                for (int ct = 0; ct < 8; ct++){
                    const int bn = ct*16 + m;
                    s16x8 kf = ldsf(&KP[bn*128 + (((kt*4 + q) ^ (bn & 15)) << 3)]);
                    s[0][ct] = mfma16(qf[0][kt], kf, s[0][ct]);
                    s[1][ct] = mfma16(qf[1][kt], kf, s[1][ct]);
                }
            }
            float alpha[2][4];
            #pragma unroll
            for (int rt = 0; rt < 2; rt++){
                #pragma unroll
                for (int i = 0; i < 4; i++){
                    float mx = s[rt][0][i];
                    #pragma unroll
                    for (int ct = 1; ct < 8; ct++) mx = fmaxf(mx, s[rt][ct][i]);
                    #pragma unroll
                    for (int off = 1; off < 16; off <<= 1) mx = fmaxf(mx, __shfl_xor(mx, off, 64));
                    const float mn = fmaxf(mrow[rt][i], mx);
                    alpha[rt][i] = __expf(mrow[rt][i] - mn);
                    float sum = 0.f;
                    #pragma unroll
                    for (int ct = 0; ct < 8; ct++){
                        const float p = __expf(s[rt][ct][i] - mn);
                        s[rt][ct][i] = p;
                        sum += p;
                    }
                    #pragma unroll
                    for (int off = 1; off < 16; off <<= 1) sum += __shfl_xor(sum, off, 64);
                    lrow[rt][i] = lrow[rt][i] * alpha[rt][i] + sum;
                    mrow[rt][i] = mn;
                }
            }
            __syncthreads();   // all waves done reading K before P overwrites it
            #pragma unroll
            for (int rt = 0; rt < 2; rt++){
                #pragma unroll
                for (int i = 0; i < 4; i++){
                    const int row = rw + rt*16 + q*4 + i;
                    #pragma unroll
                    for (int ct = 0; ct < 8; ct++)
                        KP[swz(row, ct*16 + m)] = f2bf(s[rt][ct][i]);
                }
            }
            #pragma unroll
            for (int rt = 0; rt < 2; rt++){
                #pragma unroll
                for (int ct = 0; ct < 8; ct++){
                    #pragma unroll
                    for (int i = 0; i < 4; i++) o[rt][ct][i] *= alpha[rt][i];
                }
            }
            __syncthreads();   // P visible
            #pragma unroll
            for (int kt = 0; kt < 4; kt++){
                s16x8 p0, p1;
                { const int ar = rw + m;      p0 = ldsf(&KP[ar*128 + (((kt*4 + q) ^ (ar & 15)) << 3)]); }
                { const int ar = rw + 16 + m; p1 = ldsf(&KP[ar*128 + (((kt*4 + q) ^ (ar & 15)) << 3)]); }
                #pragma unroll
                for (int ct = 0; ct < 8; ct++){
                    const int cc = ct*16 + m;
                    s16x8 vf = ldsf(&Vt[cc*128 + (((kt*4 + q) ^ (cc & 15)) << 3)]);
                    o[0][ct] = mfma16(p0, vf, o[0][ct]);
                    o[1][ct] = mfma16(p1, vf, o[1][ct]);
                }
            }
        }
        const int slot = g - (bqt * 64) / 18;
        const size_t base = (size_t)(bqt * 5 + slot) * 128;
        #pragma unroll
        for (int rt = 0; rt < 2; rt++){
            #pragma unroll
            for (int ct = 0; ct < 8; ct++){
                #pragma unroll
                for (int i = 0; i < 4; i++){
                    const int rl = rw + rt*16 + q*4 + i;
                    Opart[(base + rl)*128 + ct*16 + m] = f2bf(o[rt][ct][i]);
                }
            }
        }
        if (m == 0){
            #pragma unroll
            for (int rt = 0; rt < 2; rt++){
                #pragma unroll
                for (int i = 0; i < 4; i++){
                    const int rl = rw + rt*16 + q*4 + i;
                    Mp[base + rl] = mrow[rt][i];
                    Lp[base + rl] = lrow[rt][i];
                }
            }
        }
        u += ciN;
    }
}

// ---------------- K4: combine partials, @Wo+bo, geo-gate, +feat0, transpose ----------------
__global__ __launch_bounds__(256) void k_out(
    const u16* __restrict__ Opart, const float* __restrict__ Mp, const float* __restrict__ Lp,
    const float* __restrict__ Wo, const float* __restrict__ bo,
    const u16* __restrict__ Gb, const float* __restrict__ feat0,
    float* __restrict__ outp)
{
    __shared__ __attribute__((aligned(16))) u16 AO[128*128];
    __shared__ __attribute__((aligned(16))) u16 WoT[128*128];
    __shared__ u16 Tr[128*130];
    const int t = threadIdx.x;
    const int bqt = blockIdx.x;
    const int b = bqt / 18;
    const int r0 = (bqt % 18) * 128;
    const float rsC = 0.088388347648318447f;   // 1/sqrt(128)
    for (int idx = t; idx < 128*128; idx += 256){
        int k = idx >> 7, n = idx & 127;
        WoT[swz(n, k)] = f2bf(Wo[idx]);
    }
    const int gf = (bqt*64) / 18;
    const int gl = (bqt*64 + 63) / 18;
    const int cnt = gl - gf + 1;
    for (int idx = t; idx < 128*128; idx += 256){
        int r = idx >> 7, c = idx & 127;
        float M = -3.0e38f;
        for (int s = 0; s < cnt; s++) M = fmaxf(M, Mp[(bqt*5 + s)*128 + r]);
        float num = 0.f, den = 0.f;
        for (int s = 0; s < cnt; s++){
            float wgt = __expf(Mp[(bqt*5 + s)*128 + r] - M);
            num += wgt * bf2f(Opart[(size_t)((bqt*5 + s)*128 + r)*128 + c]);
            den += wgt * Lp[(bqt*5 + s)*128 + r];
        }
        AO[swz(r, c)] = f2bf(num / den * rsC);
    }
    __syncthreads();
    const int lane = t & 63, w = t >> 6;
    const int q = lane >> 4, m = lane & 15;
    const int rw = w * 32;
    f32x4 acc[2][8];
    #pragma unroll
    for (int rt = 0; rt < 2; rt++){
        #pragma unroll
        for (int ct = 0; ct < 8; ct++) acc[rt][ct] = fzero();
    }
    #pragma unroll
    for (int kt = 0; kt < 4; kt++){
        s16x8 a0, a1;
        { const int ar = rw + m;      a0 = ldsf(&AO[ar*128 + (((kt*4 + q) ^ (ar & 15)) << 3)]); }
        { const int ar = rw + 16 + m; a1 = ldsf(&AO[ar*128 + (((kt*4 + q) ^ (ar & 15)) << 3)]); }
        #pragma unroll
        for (int ct = 0; ct < 8; ct++){
            const int bn = ct*16 + m;
            s16x8 bb = ldsf(&WoT[bn*128 + (((kt*4 + q) ^ (bn & 15)) << 3)]);
            acc[0][ct] = mfma16(a0, bb, acc[0][ct]);
            acc[1][ct] = mfma16(a1, bb, acc[1][ct]);
        }
    }
    #pragma unroll
    for (int ct = 0; ct < 8; ct++){
        const int col = ct*16 + m;
        const float bov = bo[col];
        #pragma unroll
        for (int rt = 0; rt < 2; rt++){
            #pragma unroll
            for (int i = 0; i < 4; i++){
                const int rl = rw + rt*16 + q*4 + i;
                const float gv = bf2f(Gb[(size_t)(b*WH_ + r0 + rl)*C_ + col]);
                const float sg = 1.f / (1.f + __expf(-gv));
                Tr[rl*130 + col] = f2bf((acc[rt][ct][i] + bov) * (1.f + sg));
            }
        }
    }
    __syncthreads();
    for (int idx = t; idx < 128*128; idx += 256){
        int c = idx >> 7, wh = idx & 127;
        float v = bf2f(Tr[wh*130 + c]) + feat0[(size_t)(b*C_ + c)*WH_ + r0 + wh];
        outp[(size_t)(b*C_ + c)*WH_ + r0 + wh] = v;
    }
}

extern "C" void kernel_launch(void* const* d_in, const int* in_sizes, int n_in,
                              void* d_out, int out_size, void* d_ws, size_t ws_size,
                              hipStream_t stream)
{
    (void)in_sizes; (void)n_in; (void)out_size; (void)ws_size;
    const float* feat0 = (const float*)d_in[0];
    const float* feat1 = (const float*)d_in[1];
    const float* geo   = (const float*)d_in[2];
    const float* Wq = (const float*)d_in[3];  const float* bq = (const float*)d_in[4];
    const float* Wk = (const float*)d_in[5];  const float* bk = (const float*)d_in[6];
    const float* Wv = (const float*)d_in[7];  const float* bv = (const float*)d_in[8];
    const float* Wo = (const float*)d_in[9];  const float* bo = (const float*)d_in[10];
    const float* Wg = (const float*)d_in[11]; const float* bg = (const float*)d_in[12];
    const float* Wgate = (const float*)d_in[13]; const float* bgate = (const float*)d_in[14];
    float* outp = (float*)d_out;
    char* ws = (char*)d_ws;
    size_t off = 0;
    auto alloc = [&](size_t bytes) -> void* {
        void* p = (void*)(ws + off);
        off += (bytes + 255) & ~(size_t)255;
        return p;
    };
    u16* Qb = (u16*)alloc((size_t)B_*WH_*C_*2);      // pq (post-gate), bf16
    u16* Gb = (u16*)alloc((size_t)B_*WH_*C_*2);      // geo, bf16
    u16* Kb = (u16*)alloc((size_t)B_*N_*C_*2);       // pk [b][n][c]
    u16* Vb = (u16*)alloc((size_t)B_*N_*C_*2);       // pv^T [b][c][n]
    u16* Opart  = (u16*)alloc((size_t)144*5*128*128*2);   // flash partials, bf16
    float* Mp   = (float*)alloc((size_t)144*5*128*4);
    float* Lp   = (float*)alloc((size_t)144*5*128*4);

    k_proj_qg<<<dim3(288),  dim3(256), 0, stream>>>(feat0, geo, Wq, bq, Wg, bg, Wgate, bgate, Qb, Gb);
    k_proj_kv<<<dim3(1024), dim3(256), 0, stream>>>(feat1, Wk, bk, Wv, bv, Kb, Vb);
    k_flash  <<<dim3(512),  dim3(256), 0, stream>>>(Qb, Kb, Vb, Opart, Mp, Lp);
    k_out    <<<dim3(144),  dim3(256), 0, stream>>>(Opart, Mp, Lp, Wo, bo, Gb, feat0, outp);
}

// Round 3
// 474.048 us; speedup vs baseline: 1.2813x; 1.2813x over previous
//
#include <hip/hip_runtime.h>

#define B_ 8
#define C_ 128
#define WH_ 2304
#define N_ 8192

typedef unsigned short u16;
typedef float f32x4 __attribute__((ext_vector_type(4)));
typedef short s16x8 __attribute__((ext_vector_type(8)));

typedef const unsigned int __attribute__((address_space(1))) ga_u32;
typedef unsigned int __attribute__((address_space(3))) lds_u32;

#define LOG2E 1.4426950408889634f
#define MOFF  64.0f   // fixed softmax offset in log2 domain (no running max)

__device__ __forceinline__ float bf2f(u16 u){
    union { unsigned int i; float f; } x; x.i = ((unsigned int)u) << 16; return x.f;
}
__device__ __forceinline__ u16 f2bf(float f){
    union { float f; unsigned int i; } x; x.f = f;
    unsigned int r = x.i + 0x7fffu + ((x.i >> 16) & 1u);
    return (u16)(r >> 16);
}
// element index inside a [rows][128] bf16 LDS tile with 16B-block xor swizzle
__device__ __forceinline__ int swz(int row, int col){
    return row*128 + ((((col >> 3) ^ (row & 15)) << 3) | (col & 7));
}
__device__ __forceinline__ f32x4 fzero(){ f32x4 z = {0.f, 0.f, 0.f, 0.f}; return z; }
__device__ __forceinline__ f32x4 mfma16(s16x8 a, s16x8 b, f32x4 c){
    return __builtin_amdgcn_mfma_f32_16x16x32_bf16(a, b, c, 0, 0, 0);
}
__device__ __forceinline__ void gld16(const void* g, void* l){
    __builtin_amdgcn_global_load_lds((ga_u32*)g, (lds_u32*)l, 16, 0, 0);
}
__device__ __forceinline__ s16x8 ldsf(const u16* p){ return *(const s16x8*)p; }
__device__ __forceinline__ s16x8 cvt8(const float* p){
    s16x8 r;
    #pragma unroll
    for (int j = 0; j < 8; j++) r[j] = (short)f2bf(p[j]);
    return r;
}

// ---------------- K0: weights -> bf16 transposed [out][in] ----------------
__global__ __launch_bounds__(256) void k_prep(
    const float* __restrict__ Wq, const float* __restrict__ Wk,
    const float* __restrict__ Wv, const float* __restrict__ Wo,
    const float* __restrict__ Wg, u16* __restrict__ Wt)
{
    const int gid = blockIdx.x*256 + threadIdx.x;     // 5*16384
    const int mi = gid >> 14, e = gid & 16383;
    const int o = e >> 7, i = e & 127;
    const float* src = (mi==0)?Wq:(mi==1)?Wk:(mi==2)?Wv:(mi==3)?Wo:Wg;
    Wt[mi*16384 + o*128 + i] = f2bf(src[i*128 + o]);
}

// ---------------- K1: fused projections (qg: blocks 0..287, kv: 288..1311) --------
__global__ __launch_bounds__(256) void k_proj(
    const float* __restrict__ feat0, const float* __restrict__ geo,
    const float* __restrict__ feat1,
    const float* __restrict__ bq, const float* __restrict__ bg,
    const float* __restrict__ bk, const float* __restrict__ bv,
    const float* __restrict__ Wgate, const float* __restrict__ bgate,
    const u16* __restrict__ Wt,
    u16* __restrict__ Qb, u16* __restrict__ Gb,
    u16* __restrict__ Kb, u16* __restrict__ Vb)
{
    __shared__ __attribute__((aligned(16))) u16 At[64*128];   // 16 KB
    __shared__ __attribute__((aligned(16))) u16 Tv[128*66];   // 16.9 KB (kv only)
    const int t = threadIdx.x;
    const int lane = t & 63, w = t >> 6;
    const int q = lane >> 4, m = lane & 15;
    const int rw = w * 16;
    const u16* WqT = Wt;
    const u16* WkT = Wt + 16384;
    const u16* WvT = Wt + 32768;
    const u16* WgT = Wt + 65536;

    if (blockIdx.x < 288){
        const int b = blockIdx.x / 36;
        const int r0 = (blockIdx.x % 36) * 64;
        {   // stage feat0^T tile (transpose read)
            const int wl = t & 63;
            for (int c = t >> 6; c < 128; c += 4)
                At[swz(wl, c)] = f2bf(feat0[(size_t)(b*C_ + c)*WH_ + r0 + wl]);
        }
        __syncthreads();
        s16x8 ag[4], aq[4];
        #pragma unroll
        for (int kt = 0; kt < 4; kt++){
            const int ar = rw + m;
            aq[kt] = ldsf(&At[ar*128 + (((kt*4 + q) ^ (ar & 15)) << 3)]);
            ag[kt] = cvt8(&geo[((size_t)b*WH_ + r0 + ar)*C_ + kt*32 + q*8]);
        }
        f32x4 accq[8], accg[8];
        #pragma unroll
        for (int ct = 0; ct < 8; ct++){ accq[ct] = fzero(); accg[ct] = fzero(); }
        #pragma unroll
        for (int kt = 0; kt < 4; kt++){
            #pragma unroll
            for (int ct = 0; ct < 8; ct++){
                const int off = (ct*16 + m)*128 + kt*32 + q*8;
                accq[ct] = mfma16(aq[kt], *(const s16x8*)&WqT[off], accq[ct]);
                accg[ct] = mfma16(ag[kt], *(const s16x8*)&WgT[off], accg[ct]);
            }
        }
        float bqv[8], bgv[8], w1v[8], w2v[8];
        #pragma unroll
        for (int ct = 0; ct < 8; ct++){
            int col = ct*16 + m;
            bqv[ct] = bq[col]; bgv[ct] = bg[col];
            w1v[ct] = Wgate[col]; w2v[ct] = Wgate[C_ + col];
        }
        const float bg0 = bgate[0];
        float gs[4];
        #pragma unroll
        for (int i = 0; i < 4; i++){
            float p = 0.f;
            #pragma unroll
            for (int ct = 0; ct < 8; ct++)
                p += (accq[ct][i] + bqv[ct]) * w1v[ct] + (accg[ct][i] + bgv[ct]) * w2v[ct];
            gs[i] = p;
        }
        #pragma unroll
        for (int off = 1; off < 16; off <<= 1){
            #pragma unroll
            for (int i = 0; i < 4; i++) gs[i] += __shfl_xor(gs[i], off, 64);
        }
        #pragma unroll
        for (int i = 0; i < 4; i++){
            const float gate = 1.f / (1.f + __expf(-(gs[i] + bg0)));
            const int row = r0 + rw + q*4 + i;
            #pragma unroll
            for (int ct = 0; ct < 8; ct++){
                const int col = ct*16 + m;
                const float ge = accg[ct][i] + bgv[ct];
                const float pq = accq[ct][i] + bqv[ct] + gate * ge;
                Qb[(size_t)(b*WH_ + row)*C_ + col] = f2bf(pq * LOG2E);  // log2e folded for exp2 softmax
                Gb[(size_t)(b*WH_ + row)*C_ + col] = f2bf(ge);
            }
        }
    } else {
        const int gg = blockIdx.x - 288;
        const int b = gg >> 7;
        const int n0 = (gg & 127) * 64;
        {
            const int nl = t & 63;
            for (int c = t >> 6; c < 128; c += 4)
                At[swz(nl, c)] = f2bf(feat1[(size_t)(b*C_ + c)*N_ + n0 + nl]);
        }
        __syncthreads();
        s16x8 a[4];
        #pragma unroll
        for (int kt = 0; kt < 4; kt++){
            const int ar = rw + m;
            a[kt] = ldsf(&At[ar*128 + (((kt*4 + q) ^ (ar & 15)) << 3)]);
        }
        f32x4 ak[8], av[8];
        #pragma unroll
        for (int ct = 0; ct < 8; ct++){ ak[ct] = fzero(); av[ct] = fzero(); }
        #pragma unroll
        for (int kt = 0; kt < 4; kt++){
            #pragma unroll
            for (int ct = 0; ct < 8; ct++){
                const int off = (ct*16 + m)*128 + kt*32 + q*8;
                ak[ct] = mfma16(a[kt], *(const s16x8*)&WkT[off], ak[ct]);
                av[ct] = mfma16(a[kt], *(const s16x8*)&WvT[off], av[ct]);
            }
        }
        #pragma unroll
        for (int ct = 0; ct < 8; ct++){
            const int col = ct*16 + m;
            const float bkv = bk[col];
            const float bvv = bv[col];
            #pragma unroll
            for (int i = 0; i < 4; i++){
                const int row = n0 + rw + q*4 + i;
                Kb[(size_t)(b*N_ + row)*C_ + col] = f2bf(ak[ct][i] + bkv);
                Tv[col*66 + rw + q*4 + i] = f2bf(av[ct][i] + bvv);
            }
        }
        __syncthreads();
        for (int idx = t; idx < 128*64; idx += 256){
            int c = idx >> 6, nl = idx & 63;
            Vb[(size_t)(b*C_ + c)*N_ + n0 + nl] = Tv[c*66 + nl];
        }
    }
}

// ---------------- K2: flash attention, fixed-offset softmax, 256x512 ----------------
__global__ __launch_bounds__(512, 1) void k_flash(
    const u16* __restrict__ Qb, const u16* __restrict__ Kb, const u16* __restrict__ Vb,
    u16* __restrict__ Opart, float* __restrict__ Lp)
{
    __shared__ __attribute__((aligned(16))) u16 KP[128*128];   // K tile   (32 KB)
    __shared__ __attribute__((aligned(16))) u16 Vt[128*128];   // V^T tile (32 KB)
    __shared__ __attribute__((aligned(16))) u16 Pb[8*32*128];  // per-wave P (64 KB)
    const int t = threadIdx.x;
    const int lane = t & 63, w = t >> 6;            // 8 waves
    const int q = lane >> 4, m = lane & 15;
    const int rw = w * 32;
    const int b = blockIdx.x & 7;                   // XCD affinity: batch == blockIdx%8
    const int s = blockIdx.x >> 3;                  // slot 0..31 within batch
    u16* Pw = &Pb[w * 4096];

    s16x8 ONES;
    #pragma unroll
    for (int j = 0; j < 8; j++) ONES[j] = (short)0x3F80;  // bf16 1.0

    int u = s * 18;
    const int uend = u + 18;
    while (u < uend){
        const int qb = u >> 6;                      // q-tile (256 rows) within batch
        const int ci0 = u & 63;
        int ciN = uend - u; { int rem = 64 - ci0; if (ciN > rem) ciN = rem; }
        const size_t qrow0 = (size_t)b*WH_ + qb*256;

        s16x8 qf[2][4];
        #pragma unroll
        for (int rt = 0; rt < 2; rt++){
            #pragma unroll
            for (int kt = 0; kt < 4; kt++)
                qf[rt][kt] = *(const s16x8*)&Qb[(qrow0 + rw + rt*16 + m)*C_ + kt*32 + q*8];
        }
        f32x4 o[2][8], ol[2];
        #pragma unroll
        for (int rt = 0; rt < 2; rt++){
            ol[rt] = fzero();
            #pragma unroll
            for (int ct = 0; ct < 8; ct++) o[rt][ct] = fzero();
        }

        for (int ci = ci0; ci < ci0 + ciN; ci++){
            const int n0 = ci * 128;
            __syncthreads();   // all waves done with prev K/V
            #pragma unroll
            for (int j = 0; j < 4; j++){
                const int r = w*16 + j*4 + (lane >> 4);   // K row / V channel
                gld16(Kb + ((size_t)b*N_ + n0 + r)*C_ + ((m ^ (r & 15)) << 3),
                      &KP[(w*16 + j*4)*128]);
                gld16(Vb + ((size_t)b*C_ + r)*N_ + n0 + ((m ^ (r & 15)) << 3),
                      &Vt[(w*16 + j*4)*128]);
            }
            __syncthreads();   // K/V visible
            f32x4 sA[2][8];
            #pragma unroll
            for (int rt = 0; rt < 2; rt++){
                #pragma unroll
                for (int ct = 0; ct < 8; ct++) sA[rt][ct] = fzero();
            }
            #pragma unroll
            for (int kt = 0; kt < 4; kt++){
                #pragma unroll
                for (int ct = 0; ct < 8; ct++){
                    const int bn = ct*16 + m;
                    s16x8 kf = ldsf(&KP[bn*128 + (((kt*4 + q) ^ (bn & 15)) << 3)]);
                    sA[0][ct] = mfma16(qf[0][kt], kf, sA[0][ct]);
                    sA[1][ct] = mfma16(qf[1][kt], kf, sA[1][ct]);
                }
            }
            // fixed-offset softmax: p = 2^(s' - MOFF); no reductions, no barrier
            #pragma unroll
            for (int rt = 0; rt < 2; rt++){
                #pragma unroll
                for (int i = 0; i < 4; i++){
                    const int row = rt*16 + q*4 + i;
                    #pragma unroll
                    for (int ct = 0; ct < 8; ct++)
                        Pw[swz(row, ct*16 + m)] = f2bf(exp2f(sA[rt][ct][i] - MOFF));
                }
            }
            // PV + row-sum via ones-column (wave-private P: compiler inserts lgkmcnt)
            #pragma unroll
            for (int kt = 0; kt < 4; kt++){
                s16x8 p0 = ldsf(&Pw[m*128        + (((kt*4 + q) ^ m) << 3)]);
                s16x8 p1 = ldsf(&Pw[(16 + m)*128 + (((kt*4 + q) ^ m) << 3)]);
                #pragma unroll
                for (int ct = 0; ct < 8; ct++){
                    const int cc = ct*16 + m;
                    s16x8 vf = ldsf(&Vt[cc*128 + (((kt*4 + q) ^ (cc & 15)) << 3)]);
                    o[0][ct] = mfma16(p0, vf, o[0][ct]);
                    o[1][ct] = mfma16(p1, vf, o[1][ct]);
                }
                ol[0] = mfma16(p0, ONES, ol[0]);
                ol[1] = mfma16(p1, ONES, ol[1]);
            }
        }
        // flush partials for this q-tile
        const int sf = (qb * 64) / 18;
        const size_t pbase = ((size_t)(b*9 + qb)*5 + (s - sf)) * 256;
        #pragma unroll
        for (int rt = 0; rt < 2; rt++){
            #pragma unroll
            for (int ct = 0; ct < 8; ct++){
                #pragma unroll
                for (int i = 0; i < 4; i++){
                    const int rl = rw + rt*16 + q*4 + i;
                    Opart[(pbase + rl)*128 + ct*16 + m] = f2bf(o[rt][ct][i]);
                }
            }
        }
        if (m == 0){
            #pragma unroll
            for (int rt = 0; rt < 2; rt++){
                #pragma unroll
                for (int i = 0; i < 4; i++)
                    Lp[pbase + rw + rt*16 + q*4 + i] = ol[rt][i];
            }
        }
        u += ciN;
    }
}

// ---------------- K3: combine partials, @Wo+bo, geo-gate, +feat0, transpose --------
__global__ __launch_bounds__(256) void k_out(
    const u16* __restrict__ Opart, const float* __restrict__ Lp,
    const float* __restrict__ bo, const u16* __restrict__ Wt,
    const u16* __restrict__ Gb, const float* __restrict__ feat0,
    float* __restrict__ outp)
{
    __shared__ __attribute__((aligned(16))) u16 AO[128*128];   // 32 KB
    __shared__ u16 Tr[128*130];                                 // 33.3 KB
    const int t = threadIdx.x;
    const int bqt = blockIdx.x;                 // 0..143 (half q-tiles of 128 rows)
    const int qt2 = bqt >> 1, half = bqt & 1;
    const int b = qt2 / 9, qb = qt2 % 9;
    const int gr0 = qb*256 + half*128;          // row base within batch
    const u16* WoT = Wt + 49152;
    const float rsC = 0.088388347648318447f;    // 1/sqrt(128)
    const int sf = (qb*64) / 18;
    const int sl = (qb*64 + 63) / 18;
    const int cnt = sl - sf + 1;
    for (int idx = t; idx < 128*128; idx += 256){
        int r = idx >> 7, c = idx & 127;
        float num = 0.f, den = 0.f;
        for (int ss = 0; ss < cnt; ss++){
            const size_t base = ((size_t)qt2*5 + ss)*256 + half*128 + r;
            num += bf2f(Opart[base*128 + c]);
            den += Lp[base];
        }
        AO[swz(r, c)] = f2bf(num / den * rsC);
    }
    __syncthreads();
    const int lane = t & 63, w = t >> 6;
    const int q = lane >> 4, m = lane & 15;
    const int rw = w * 32;
    f32x4 acc[2][8];
    #pragma unroll
    for (int rt = 0; rt < 2; rt++){
        #pragma unroll
        for (int ct = 0; ct < 8; ct++) acc[rt][ct] = fzero();
    }
    #pragma unroll
    for (int kt = 0; kt < 4; kt++){
        s16x8 a0, a1;
        { const int ar = rw + m;      a0 = ldsf(&AO[ar*128 + (((kt*4 + q) ^ (ar & 15)) << 3)]); }
        { const int ar = rw + 16 + m; a1 = ldsf(&AO[ar*128 + (((kt*4 + q) ^ (ar & 15)) << 3)]); }
        #pragma unroll
        for (int ct = 0; ct < 8; ct++){
            const s16x8 bb = *(const s16x8*)&WoT[(ct*16 + m)*128 + kt*32 + q*8];
            acc[0][ct] = mfma16(a0, bb, acc[0][ct]);
            acc[1][ct] = mfma16(a1, bb, acc[1][ct]);
        }
    }
    #pragma unroll
    for (int ct = 0; ct < 8; ct++){
        const int col = ct*16 + m;
        const float bov = bo[col];
        #pragma unroll
        for (int rt = 0; rt < 2; rt++){
            #pragma unroll
            for (int i = 0; i < 4; i++){
                const int rl = rw + rt*16 + q*4 + i;
                const float gv = bf2f(Gb[((size_t)b*WH_ + gr0 + rl)*C_ + col]);
                const float sg = 1.f / (1.f + __expf(-gv));
                Tr[rl*130 + col] = f2bf((acc[rt][ct][i] + bov) * (1.f + sg));
            }
        }
    }
    __syncthreads();
    for (int idx = t; idx < 128*128; idx += 256){
        int c = idx >> 7, wh = idx & 127;
        float v = bf2f(Tr[wh*130 + c]) + feat0[(size_t)(b*C_ + c)*WH_ + gr0 + wh];
        outp[(size_t)(b*C_ + c)*WH_ + gr0 + wh] = v;
    }
}

extern "C" void kernel_launch(void* const* d_in, const int* in_sizes, int n_in,
                              void* d_out, int out_size, void* d_ws, size_t ws_size,
                              hipStream_t stream)
{
    (void)in_sizes; (void)n_in; (void)out_size; (void)ws_size;
    const float* feat0 = (const float*)d_in[0];
    const float* feat1 = (const float*)d_in[1];
    const float* geo   = (const float*)d_in[2];
    const float* Wq = (const float*)d_in[3];  const float* bq = (const float*)d_in[4];
    const float* Wk = (const float*)d_in[5];  const float* bk = (const float*)d_in[6];
    const float* Wv = (const float*)d_in[7];  const float* bv = (const float*)d_in[8];
    const float* Wo = (const float*)d_in[9];  const float* bo = (const float*)d_in[10];
    const float* Wg = (const float*)d_in[11]; const float* bg = (const float*)d_in[12];
    const float* Wgate = (const float*)d_in[13]; const float* bgate = (const float*)d_in[14];
    float* outp = (float*)d_out;
    char* ws = (char*)d_ws;
    size_t off = 0;
    auto alloc = [&](size_t bytes) -> void* {
        void* p = (void*)(ws + off);
        off += (bytes + 255) & ~(size_t)255;
        return p;
    };
    u16* Qb = (u16*)alloc((size_t)B_*WH_*C_*2);         // pq (gated, x log2e)
    u16* Gb = (u16*)alloc((size_t)B_*WH_*C_*2);         // geo proj
    u16* Kb = (u16*)alloc((size_t)B_*N_*C_*2);          // pk [b][n][c]
    u16* Vb = (u16*)alloc((size_t)B_*N_*C_*2);          // pv^T [b][c][n]
    u16* Opart = (u16*)alloc((size_t)72*5*256*128*2);   // flash partials
    float* Lp  = (float*)alloc((size_t)72*5*256*4);     // partial row sums
    u16* Wt = (u16*)alloc((size_t)5*16384*2);           // bf16 transposed weights

    k_prep <<<dim3(320),  dim3(256), 0, stream>>>(Wq, Wk, Wv, Wo, Wg, Wt);
    k_proj <<<dim3(1312), dim3(256), 0, stream>>>(feat0, geo, feat1, bq, bg, bk, bv,
                                                  Wgate, bgate, Wt, Qb, Gb, Kb, Vb);
    k_flash<<<dim3(256),  dim3(512), 0, stream>>>(Qb, Kb, Vb, Opart, Lp);
    k_out  <<<dim3(144),  dim3(256), 0, stream>>>(Opart, Lp, bo, Wt, Gb, feat0, outp);
}